// Round 10
// baseline (681.435 us; speedup 1.0000x reference)
//
#include <hip/hip_runtime.h>
#include <hip/hip_bf16.h>
#include <stdint.h>

// LeviCivitaKAN: c = pp@lw^T + x@w1^T; LN(c)*gamma+beta
// bf16 MFMA GEMM, concatenated K (4096 pairs + 1024 base) = 5120.
// GEMM v8: ROTATED 4-window schedule. The last MFMA quad of tile kt-1 is
// carried in registers across the certify barrier and executed in W1(kt)
// while W1's reads for tile kt are in flight -> no cold-start lgkm stall in
// any window. Exactly 4 register quads rotate (A0r,A1r,B0r,B1r), peak live
// = R7's. Staging, T2 swizzle, vmcnt(4) certify identical to R7 (audited).

#define IN_F 1024
#define OUT_F 1024
#define N_PAIRS 4096
#define BATCH_N 32768
#define KTOT (N_PAIRS + IN_F)   // 5120
#define EPS_LN 1e-5f

#define BM 256
#define BN 256
#define BK 64
#define NKT (KTOT / BK)         // 80 K-tiles
#define RS ((size_t)KTOT * 2)   // global row stride bytes

typedef __attribute__((ext_vector_type(8))) __bf16 bf16x8;
typedef __attribute__((ext_vector_type(4))) float f32x4;

__device__ __forceinline__ unsigned short f32_to_bf16_bits(float f) {
  union { float f; unsigned u; } c; c.f = f;
  unsigned r = c.u + 0x7FFFu + ((c.u >> 16) & 1u);   // RNE
  return (unsigned short)(r >> 16);
}

__device__ __forceinline__ float bf16_bits_to_f32(unsigned short b) {
  union { unsigned u; float f; } c; c.u = ((unsigned)b) << 16;
  return c.f;
}

__device__ __forceinline__ void gload_lds16(const void* g, void* l) {
  __builtin_amdgcn_global_load_lds(
      (const __attribute__((address_space(1))) void*)g,
      (__attribute__((address_space(3))) void*)l, 16, 0, 0);
}

// ---------------- k0: weight concat + fp32->bf16 ----------------
__global__ __launch_bounds__(256) void prep_w_kernel(
    const float* __restrict__ lw, const float* __restrict__ w1,
    unsigned short* __restrict__ Wcat) {
  int t = blockIdx.x * 256 + threadIdx.x;
  int e = t * 4;
  int o = e / KTOT;
  int k = e - o * KTOT;
  const float* src = (k < N_PAIRS) ? (lw + (size_t)o * N_PAIRS + k)
                                   : (w1 + (size_t)o * IN_F + (k - N_PAIRS));
  float4 v = *reinterpret_cast<const float4*>(src);
  ushort4 b;
  b.x = f32_to_bf16_bits(v.x);
  b.y = f32_to_bf16_bits(v.y);
  b.z = f32_to_bf16_bits(v.z);
  b.w = f32_to_bf16_bits(v.w);
  *reinterpret_cast<ushort4*>(Wcat + e) = b;
}

// ---------------- k1: per-row pp + bf16(x) -> Xcat ----------------
__global__ __launch_bounds__(256) void prep_x_kernel(
    const float* __restrict__ x,
    const int* __restrict__ idx_i, const int* __restrict__ idx_j,
    const float* __restrict__ scale, const float* __restrict__ translation,
    unsigned short* __restrict__ Xcat, int rowBase) {
  __shared__ float xs[IN_F];
  int r = blockIdx.x;
  int t = threadIdx.x;
  const float* xrow = x + (size_t)(rowBase + r) * IN_F;
  float4 xv = reinterpret_cast<const float4*>(xrow)[t];
  float4 sv = reinterpret_cast<const float4*>(scale)[t];
  float4 tv = reinterpret_cast<const float4*>(translation)[t];
  float4 xsv;
  xsv.x = (xv.x - tv.x) / sv.x;
  xsv.y = (xv.y - tv.y) / sv.y;
  xsv.z = (xv.z - tv.z) / sv.z;
  xsv.w = (xv.w - tv.w) / sv.w;
  reinterpret_cast<float4*>(xs)[t] = xsv;

  unsigned short* rowout = Xcat + (size_t)r * KTOT;
  ushort4 xb;
  xb.x = f32_to_bf16_bits(xv.x);
  xb.y = f32_to_bf16_bits(xv.y);
  xb.z = f32_to_bf16_bits(xv.z);
  xb.w = f32_to_bf16_bits(xv.w);
  *reinterpret_cast<ushort4*>(rowout + N_PAIRS + t * 4) = xb;

  __syncthreads();
#pragma unroll
  for (int g = 0; g < 2; ++g) {
    int p = (g * 256 + t) * 8;
    int4 ia = *reinterpret_cast<const int4*>(idx_i + p);
    int4 ib = *reinterpret_cast<const int4*>(idx_i + p + 4);
    int4 ja = *reinterpret_cast<const int4*>(idx_j + p);
    int4 jb = *reinterpret_cast<const int4*>(idx_j + p + 4);
    ushort4 oa, ob;
    oa.x = f32_to_bf16_bits(xs[ia.x] * xs[ja.x]);
    oa.y = f32_to_bf16_bits(xs[ia.y] * xs[ja.y]);
    oa.z = f32_to_bf16_bits(xs[ia.z] * xs[ja.z]);
    oa.w = f32_to_bf16_bits(xs[ia.w] * xs[ja.w]);
    ob.x = f32_to_bf16_bits(xs[ib.x] * xs[jb.x]);
    ob.y = f32_to_bf16_bits(xs[ib.y] * xs[jb.y]);
    ob.z = f32_to_bf16_bits(xs[ib.z] * xs[jb.z]);
    ob.w = f32_to_bf16_bits(xs[ib.w] * xs[jb.w]);
    *reinterpret_cast<ushort4*>(rowout + p) = oa;
    *reinterpret_cast<ushort4*>(rowout + p + 4) = ob;
  }
}

// ---------------- k2: bf16 GEMM, rotated 4-window schedule ----------------
// LDS per parity (64 KiB): rg 0=B0(rows0-127) 1=B1 2=A0 3=A1, each 16 KiB,
// row stride 128 B, kb_lds = kb ^ ((row&7)<<4). Half-tile h: kt=h>>2, rg=h&3.

#define STAGE_HALF(h_)                                                        \
  {                                                                           \
    int h__ = (h_);                                                           \
    if (h__ < 4 * NKT) {                                                      \
      int kt__ = h__ >> 2, rg__ = h__ & 3;                                    \
      const char* mb__ = (rg__ < 2) ? Bb : Ab;                                \
      const char* src__ = mb__ + (size_t)((rg__ & 1) * 128 + srow) * RS +     \
                          (size_t)kt__ * 128 + skb;                           \
      char* dst__ = lds + ((kt__ & 1) << 16) + (rg__ << 14) + (w << 10);      \
      gload_lds16(src__, dst__);                                              \
      gload_lds16(src__ + (size_t)64 * RS, dst__ + 8192);                     \
    }                                                                         \
  }

#define MFMA_Q(mb, amv, bv)                                                   \
  __builtin_amdgcn_s_setprio(1);                                              \
  _Pragma("unroll") for (int i_ = 0; i_ < 4; ++i_)                            \
      _Pragma("unroll") for (int n_ = 0; n_ < 4; ++n_)                        \
    acc[(mb) + i_][n_] = __builtin_amdgcn_mfma_f32_16x16x32_bf16(             \
        amv[i_], bv[n_], acc[(mb) + i_][n_], 0, 0, 0);                        \
  __builtin_amdgcn_s_setprio(0);

// One rotated K-tile. bo compile-time (0 / 65536). W1M=0 for the kt=0 peel.
// Rotation invariant at W1 entry: A1r=a3(kt-1), B1r=bf1(kt-1), tile kt
// certified in LDS by the preceding barrier.
#define ROT_KTILE(ktv, bo, W1M)                                               \
  {                                                                           \
    const int kt_c = (ktv);                                                   \
    /* W1: read bf0,a0(kt); MFMA(m4-7) of kt-1 from carried regs */           \
    _Pragma("unroll") for (int n = 0; n < 4; ++n)                             \
        B0r[n] = *(const bf16x8*)(bRow + (bo) + n * 2048 + kb0);              \
    _Pragma("unroll") for (int i = 0; i < 4; ++i)                             \
        A0r[i] = *(const bf16x8*)(aRow + (bo) + i * 2048 + kb0);              \
    if (W1M) { MFMA_Q(4, A1r, B1r); }                                         \
    __builtin_amdgcn_s_barrier();                                             \
    /* W2: read bf1,a1(kt); stage A0,A1(kt+1); MFMA(m0-3,k0) */               \
    _Pragma("unroll") for (int n = 0; n < 4; ++n)                             \
        B1r[n] = *(const bf16x8*)(bRow + (bo) + n * 2048 + kb1);              \
    _Pragma("unroll") for (int i = 0; i < 4; ++i)                             \
        A1r[i] = *(const bf16x8*)(aRow + (bo) + i * 2048 + kb1);              \
    STAGE_HALF(4 * (kt_c + 1) + 2);                                           \
    STAGE_HALF(4 * (kt_c + 1) + 3);                                           \
    MFMA_Q(0, A0r, B0r);                                                      \
    __builtin_amdgcn_s_barrier();                                             \
    /* W3: read a2(kt) into A0r; stage B0(kt+2); MFMA(m0-3,k1) */             \
    _Pragma("unroll") for (int i = 0; i < 4; ++i)                             \
        A0r[i] = *(const bf16x8*)(aRow + (bo) + (4 + i) * 2048 + kb0);        \
    STAGE_HALF(4 * (kt_c + 2) + 0);                                           \
    MFMA_Q(0, A1r, B1r);                                                      \
    __builtin_amdgcn_s_barrier();                                             \
    /* W4: read a3(kt) into A1r; stage B1(kt+2); MFMA(m4-7,k0); certify */    \
    _Pragma("unroll") for (int i = 0; i < 4; ++i)                             \
        A1r[i] = *(const bf16x8*)(aRow + (bo) + (4 + i) * 2048 + kb1);        \
    STAGE_HALF(4 * (kt_c + 2) + 1);                                           \
    MFMA_Q(4, A0r, B0r);                                                      \
    if (kt_c + 2 < NKT) {                                                     \
      asm volatile("s_waitcnt vmcnt(4)" ::: "memory");                        \
    } else if (kt_c + 1 < NKT) {                                              \
      asm volatile("s_waitcnt vmcnt(0)" ::: "memory");                        \
    }                                                                         \
    __builtin_amdgcn_s_barrier();                                             \
  }

__global__ __launch_bounds__(512, 2) void gemm_kernel(
    const unsigned short* __restrict__ A,    // [Mc][KTOT] bf16 bits
    const unsigned short* __restrict__ Bw,   // [OUT_F][KTOT] bf16 bits
    unsigned short* __restrict__ Cb) {       // [Mc][OUT_F] bf16 bits
  __shared__ __align__(16) char lds[131072];

  int nwg = gridDim.x;                 // multiple of 8
  int bid = blockIdx.x;
  int cpx = nwg >> 3;
  int swz = (bid & 7) * cpx + (bid >> 3);   // T1 XCD swizzle
  int rt = swz >> 2;                   // OUT_F/BN = 4 col tiles
  int ct = swz & 3;

  int tid = threadIdx.x;
  int lane = tid & 63;
  int w = tid >> 6;                    // 0..7
  int wr = w >> 2;                     // 0..1
  int wc = w & 3;                      // 0..3

  const char* Ab = (const char*)A + (size_t)rt * BM * RS;
  const char* Bb = (const char*)Bw + (size_t)ct * BN * RS;

  // staging geometry
  int srow = tid >> 3;                                   // 0..63
  int skb = ((tid & 7) << 4) ^ (((tid >> 3) & 7) << 4);  // inverse swizzle

  // read-side geometry
  int lane15 = lane & 15;
  int cb = lane >> 4;
  int swzm = (lane15 & 7) << 4;
  int kb0 = (cb << 4) ^ swzm;          // ks=0 swizzled K-byte
  int kb1 = (64 + (cb << 4)) ^ swzm;   // ks=1
  const char* aRow = lds + 32768 + (wr * 128 + lane15) * 128;
  const char* bRow = lds + (wc * 64 + lane15) * 128;

  f32x4 acc[8][4];
#pragma unroll
  for (int m = 0; m < 8; ++m)
#pragma unroll
    for (int n = 0; n < 4; ++n) acc[m][n] = {0.f, 0.f, 0.f, 0.f};

  bf16x8 A0r[4], A1r[4], B0r[4], B1r[4];

  // prologue: B0(0),B1(0),A0(0),A1(0),B0(1),B1(1) in pinned order
#pragma unroll
  for (int hp = 0; hp < 6; ++hp) {
    STAGE_HALF(hp);
    __builtin_amdgcn_sched_barrier(0);
  }
  asm volatile("s_waitcnt vmcnt(4)" ::: "memory");   // tile 0 landed
  __builtin_amdgcn_s_barrier();                      // ... for ALL waves

  ROT_KTILE(0, 0, 0);        // peel: no carried quad yet
  ROT_KTILE(1, 65536, 1);
  for (int kt = 2; kt < NKT; kt += 2) {
    ROT_KTILE(kt, 0, 1);
    ROT_KTILE(kt + 1, 65536, 1);
  }
  MFMA_Q(4, A1r, B1r);       // drain: last quad of tile NKT-1

  // epilogue: C row = (lane>>4)*4 + j, col = lane&15 (m89 layout); bf16 store
  int crow0 = rt * BM + wr * 128 + (cb << 2);
  int ccol0 = ct * BN + wc * 64 + lane15;
#pragma unroll
  for (int m = 0; m < 8; ++m)
#pragma unroll
    for (int n = 0; n < 4; ++n)
#pragma unroll
      for (int j = 0; j < 4; ++j)
        Cb[(size_t)(crow0 + m * 16 + j) * OUT_F + ccol0 + n * 16] =
            f32_to_bf16_bits(acc[m][n][j]);
}

// ---------------- k3: LayerNorm, bf16 C -> fp32 out ----------------
__global__ __launch_bounds__(256) void ln_kernel(
    const unsigned short* __restrict__ Cb, float* __restrict__ out,
    const float* __restrict__ gamma, const float* __restrict__ beta) {
  int r = blockIdx.x;
  int t = threadIdx.x;
  ushort4 u = reinterpret_cast<const ushort4*>(Cb + (size_t)r * OUT_F)[t];
  float4 v;
  v.x = bf16_bits_to_f32(u.x);
  v.y = bf16_bits_to_f32(u.y);
  v.z = bf16_bits_to_f32(u.z);
  v.w = bf16_bits_to_f32(u.w);
  float s = v.x + v.y + v.z + v.w;
  float s2 = v.x * v.x + v.y * v.y + v.z * v.z + v.w * v.w;
#pragma unroll
  for (int off = 32; off > 0; off >>= 1) {
    s += __shfl_down(s, off, 64);
    s2 += __shfl_down(s2, off, 64);
  }
  __shared__ float ps[4], ps2[4];
  int lane = t & 63, wid = t >> 6;
  if (lane == 0) { ps[wid] = s; ps2[wid] = s2; }
  __syncthreads();
  float fs = ps[0] + ps[1] + ps[2] + ps[3];
  float fs2 = ps2[0] + ps2[1] + ps2[2] + ps2[3];
  float mu = fs * (1.0f / OUT_F);
  float var = fs2 * (1.0f / OUT_F) - mu * mu;
  float rstd = rsqrtf(var + EPS_LN);
  float4 g = reinterpret_cast<const float4*>(gamma)[t];
  float4 b = reinterpret_cast<const float4*>(beta)[t];
  float4 o;
  o.x = (v.x - mu) * rstd * g.x + b.x;
  o.y = (v.y - mu) * rstd * g.y + b.y;
  o.z = (v.z - mu) * rstd * g.z + b.z;
  o.w = (v.w - mu) * rstd * g.w + b.w;
  reinterpret_cast<float4*>(out + (size_t)r * OUT_F)[t] = o;
}

// ---------------- launch ----------------
extern "C" void kernel_launch(void* const* d_in, const int* in_sizes, int n_in,
                              void* d_out, int out_size, void* d_ws, size_t ws_size,
                              hipStream_t stream) {
  const float* x           = (const float*)d_in[0];
  const int*   idx_i       = (const int*)d_in[1];
  const int*   idx_j       = (const int*)d_in[2];
  const float* scale       = (const float*)d_in[3];
  const float* translation = (const float*)d_in[4];
  const float* lw          = (const float*)d_in[5];
  const float* w1          = (const float*)d_in[6];
  const float* gamma       = (const float*)d_in[7];
  const float* beta        = (const float*)d_in[8];
  float* out = (float*)d_out;

  unsigned short* Wcat = (unsigned short*)d_ws;
  size_t wcat_bytes = (size_t)OUT_F * KTOT * 2;          // 10.5 MB
  size_t avail = ws_size > wcat_bytes ? ws_size - wcat_bytes : 0;

  // per-chunk: Xcat chunk*KTOT*2 + Cb chunk*OUT_F*2 bytes
  int chunk = BATCH_N;
  while (chunk > 512 && (size_t)chunk * (KTOT * 2 + OUT_F * 2) > avail) chunk >>= 1;

  unsigned short* Cb = (unsigned short*)((char*)d_ws + wcat_bytes);
  unsigned short* Xcat = Cb + (size_t)chunk * OUT_F;

  prep_w_kernel<<<dim3(OUT_F * KTOT / 4 / 256), dim3(256), 0, stream>>>(lw, w1, Wcat);

  for (int rb = 0; rb < BATCH_N; rb += chunk) {
    prep_x_kernel<<<dim3(chunk), dim3(256), 0, stream>>>(
        x, idx_i, idx_j, scale, translation, Xcat, rb);
    gemm_kernel<<<dim3((chunk / BM) * (OUT_F / BN)), dim3(512), 0, stream>>>(
        Xcat, Wcat, Cb);
    ln_kernel<<<dim3(chunk), dim3(256), 0, stream>>>(
        Cb, out + (size_t)rb * OUT_F, gamma, beta);
  }
}

// Round 11
// 421.695 us; speedup vs baseline: 1.6159x; 1.6159x over previous
//
#include <hip/hip_runtime.h>
#include <hip/hip_bf16.h>
#include <stdint.h>

// LeviCivitaKAN: c = pp@lw^T + x@w1^T; LN(c)*gamma+beta
// bf16 MFMA GEMM, concatenated K (4096 pairs + 1024 base) = 5120.
// GEMM v5 (BEST, reverted from failed v6/v7/v8 experiments):
// overlapped 4-barrier/K-tile schedule, no hard lgkm fences (compiler emits
// fine-grained counted lgkmcnt), kt unrolled x2 (bo compile-time).
// Per-window: {ds_reads for next phase || stage 1-2 half-tiles || 16 MFMA}.
// Staged-data RAW certified by counted vmcnt(4) before K-tile-end barrier.
// T1 XCD swizzle, T2 XOR swizzle (0 bank conflicts), T5 setprio.
// Measured: gemm 276us = 1245 TF, MfmaUtil 57%, 0 spills.
// Structural note: LDS traffic 224KB/K-tile/block ~ 1750cy floor at 128B/cy;
// measured ~2070cy -> ~85% of LDS-BW roofline. A-reads 4x / B-reads 2x
// wave-duplicated (no cross-wave LDS broadcast) -- inherent at 128x64/wave.

#define IN_F 1024
#define OUT_F 1024
#define N_PAIRS 4096
#define BATCH_N 32768
#define KTOT (N_PAIRS + IN_F)   // 5120
#define EPS_LN 1e-5f

#define BM 256
#define BN 256
#define BK 64
#define NKT (KTOT / BK)         // 80 K-tiles
#define RS ((size_t)KTOT * 2)   // global row stride bytes

typedef __attribute__((ext_vector_type(8))) __bf16 bf16x8;
typedef __attribute__((ext_vector_type(4))) float f32x4;

__device__ __forceinline__ unsigned short f32_to_bf16_bits(float f) {
  union { float f; unsigned u; } c; c.f = f;
  unsigned r = c.u + 0x7FFFu + ((c.u >> 16) & 1u);   // RNE
  return (unsigned short)(r >> 16);
}

__device__ __forceinline__ float bf16_bits_to_f32(unsigned short b) {
  union { unsigned u; float f; } c; c.u = ((unsigned)b) << 16;
  return c.f;
}

__device__ __forceinline__ void gload_lds16(const void* g, void* l) {
  __builtin_amdgcn_global_load_lds(
      (const __attribute__((address_space(1))) void*)g,
      (__attribute__((address_space(3))) void*)l, 16, 0, 0);
}

// ---------------- k0: weight concat + fp32->bf16 ----------------
__global__ __launch_bounds__(256) void prep_w_kernel(
    const float* __restrict__ lw, const float* __restrict__ w1,
    unsigned short* __restrict__ Wcat) {
  int t = blockIdx.x * 256 + threadIdx.x;
  int e = t * 4;
  int o = e / KTOT;
  int k = e - o * KTOT;
  const float* src = (k < N_PAIRS) ? (lw + (size_t)o * N_PAIRS + k)
                                   : (w1 + (size_t)o * IN_F + (k - N_PAIRS));
  float4 v = *reinterpret_cast<const float4*>(src);
  ushort4 b;
  b.x = f32_to_bf16_bits(v.x);
  b.y = f32_to_bf16_bits(v.y);
  b.z = f32_to_bf16_bits(v.z);
  b.w = f32_to_bf16_bits(v.w);
  *reinterpret_cast<ushort4*>(Wcat + e) = b;
}

// ---------------- k1: per-row pp + bf16(x) -> Xcat ----------------
__global__ __launch_bounds__(256) void prep_x_kernel(
    const float* __restrict__ x,
    const int* __restrict__ idx_i, const int* __restrict__ idx_j,
    const float* __restrict__ scale, const float* __restrict__ translation,
    unsigned short* __restrict__ Xcat, int rowBase) {
  __shared__ float xs[IN_F];
  int r = blockIdx.x;
  int t = threadIdx.x;
  const float* xrow = x + (size_t)(rowBase + r) * IN_F;
  float4 xv = reinterpret_cast<const float4*>(xrow)[t];
  float4 sv = reinterpret_cast<const float4*>(scale)[t];
  float4 tv = reinterpret_cast<const float4*>(translation)[t];
  float4 xsv;
  xsv.x = (xv.x - tv.x) / sv.x;
  xsv.y = (xv.y - tv.y) / sv.y;
  xsv.z = (xv.z - tv.z) / sv.z;
  xsv.w = (xv.w - tv.w) / sv.w;
  reinterpret_cast<float4*>(xs)[t] = xsv;

  unsigned short* rowout = Xcat + (size_t)r * KTOT;
  ushort4 xb;
  xb.x = f32_to_bf16_bits(xv.x);
  xb.y = f32_to_bf16_bits(xv.y);
  xb.z = f32_to_bf16_bits(xv.z);
  xb.w = f32_to_bf16_bits(xv.w);
  *reinterpret_cast<ushort4*>(rowout + N_PAIRS + t * 4) = xb;

  __syncthreads();
#pragma unroll
  for (int g = 0; g < 2; ++g) {
    int p = (g * 256 + t) * 8;
    int4 ia = *reinterpret_cast<const int4*>(idx_i + p);
    int4 ib = *reinterpret_cast<const int4*>(idx_i + p + 4);
    int4 ja = *reinterpret_cast<const int4*>(idx_j + p);
    int4 jb = *reinterpret_cast<const int4*>(idx_j + p + 4);
    ushort4 oa, ob;
    oa.x = f32_to_bf16_bits(xs[ia.x] * xs[ja.x]);
    oa.y = f32_to_bf16_bits(xs[ia.y] * xs[ja.y]);
    oa.z = f32_to_bf16_bits(xs[ia.z] * xs[ja.z]);
    oa.w = f32_to_bf16_bits(xs[ia.w] * xs[ja.w]);
    ob.x = f32_to_bf16_bits(xs[ib.x] * xs[jb.x]);
    ob.y = f32_to_bf16_bits(xs[ib.y] * xs[jb.y]);
    ob.z = f32_to_bf16_bits(xs[ib.z] * xs[jb.z]);
    ob.w = f32_to_bf16_bits(xs[ib.w] * xs[jb.w]);
    *reinterpret_cast<ushort4*>(rowout + p) = oa;
    *reinterpret_cast<ushort4*>(rowout + p + 4) = ob;
  }
}

// ---------------- k2: bf16 GEMM, overlapped schedule v5 ----------------
// LDS per parity (64 KiB): rg 0=B0(rows0-127) 1=B1 2=A0 3=A1, each 16 KiB,
// row stride 128 B, kb_lds = kb ^ ((row&7)<<4). Half-tile h: kt=h>>2, rg=h&3.
// Stage points (window of kt): W1: A0(kt+1), W2: A1(kt+1), W3: B0(kt+2),
// W4: B1(kt+2). vmcnt(4) before K-tile-end barrier certifies tile kt+1.

#define STAGE_HALF(h_)                                                        \
  {                                                                           \
    int h__ = (h_);                                                           \
    if (h__ < 4 * NKT) {                                                      \
      int kt__ = h__ >> 2, rg__ = h__ & 3;                                    \
      const char* mb__ = (rg__ < 2) ? Bb : Ab;                                \
      const char* src__ = mb__ + (size_t)((rg__ & 1) * 128 + srow) * RS +     \
                          (size_t)kt__ * 128 + skb;                           \
      char* dst__ = lds + ((kt__ & 1) << 16) + (rg__ << 14) + (w << 10);      \
      gload_lds16(src__, dst__);                                              \
      gload_lds16(src__ + (size_t)64 * RS, dst__ + 8192);                     \
    }                                                                         \
  }

#define MFMA_Q(mb, amv, bv)                                                   \
  __builtin_amdgcn_s_setprio(1);                                              \
  _Pragma("unroll") for (int i_ = 0; i_ < 4; ++i_)                            \
      _Pragma("unroll") for (int n_ = 0; n_ < 4; ++n_)                        \
    acc[(mb) + i_][n_] = __builtin_amdgcn_mfma_f32_16x16x32_bf16(             \
        amv[i_], bv[n_], acc[(mb) + i_][n_], 0, 0, 0);                        \
  __builtin_amdgcn_s_setprio(0);

// One K-tile, bo = compile-time buffer byte offset (0 or 65536).
#define KTILE_BODY(ktv, bo)                                                   \
  {                                                                           \
    const int kt_c = (ktv);                                                   \
    bf16x8 bf0[4], bf1[4], a0[4], a1[4], a2[4], a3[4];                        \
    /* W1: reads for m0-3.k0 + m0-3.k1; stage A0(kt+1); MFMA m0-3.k0 */       \
    _Pragma("unroll") for (int n = 0; n < 4; ++n)                             \
        bf0[n] = *(const bf16x8*)(bRow + (bo) + n * 2048 + kb0);              \
    _Pragma("unroll") for (int i = 0; i < 4; ++i)                             \
        a0[i] = *(const bf16x8*)(aRow + (bo) + i * 2048 + kb0);               \
    STAGE_HALF(4 * (kt_c + 1) + 2);                                           \
    MFMA_Q(0, a0, bf0);                                                       \
    _Pragma("unroll") for (int n = 0; n < 4; ++n)                             \
        bf1[n] = *(const bf16x8*)(bRow + (bo) + n * 2048 + kb1);              \
    _Pragma("unroll") for (int i = 0; i < 4; ++i)                             \
        a1[i] = *(const bf16x8*)(aRow + (bo) + i * 2048 + kb1);               \
    __builtin_amdgcn_s_barrier();                                             \
    /* W2: MFMA m0-3.k1; reads m4-7.k0; stage A1(kt+1) */                     \
    MFMA_Q(0, a1, bf1);                                                       \
    _Pragma("unroll") for (int i = 0; i < 4; ++i)                             \
        a2[i] = *(const bf16x8*)(aRow + (bo) + (4 + i) * 2048 + kb0);         \
    STAGE_HALF(4 * (kt_c + 1) + 3);                                           \
    __builtin_amdgcn_s_barrier();                                             \
    /* W3: MFMA m4-7.k0; reads m4-7.k1; stage B0(kt+2) */                     \
    MFMA_Q(4, a2, bf0);                                                       \
    _Pragma("unroll") for (int i = 0; i < 4; ++i)                             \
        a3[i] = *(const bf16x8*)(aRow + (bo) + (4 + i) * 2048 + kb1);         \
    STAGE_HALF(4 * (kt_c + 2) + 0);                                           \
    __builtin_amdgcn_s_barrier();                                             \
    /* W4: MFMA m4-7.k1; stage B1(kt+2); certify tile kt+1 */                 \
    MFMA_Q(4, a3, bf1);                                                       \
    STAGE_HALF(4 * (kt_c + 2) + 1);                                           \
    if (kt_c + 2 < NKT) {                                                     \
      asm volatile("s_waitcnt vmcnt(4)" ::: "memory");                        \
    } else if (kt_c + 1 < NKT) {                                              \
      asm volatile("s_waitcnt vmcnt(0)" ::: "memory");                        \
    }                                                                         \
    __builtin_amdgcn_s_barrier();                                             \
  }

__global__ __launch_bounds__(512, 2) void gemm_kernel(
    const unsigned short* __restrict__ A,    // [Mc][KTOT] bf16 bits
    const unsigned short* __restrict__ Bw,   // [OUT_F][KTOT] bf16 bits
    unsigned short* __restrict__ Cb) {       // [Mc][OUT_F] bf16 bits
  __shared__ __align__(16) char lds[131072];

  int nwg = gridDim.x;                 // multiple of 8
  int bid = blockIdx.x;
  int cpx = nwg >> 3;
  int swz = (bid & 7) * cpx + (bid >> 3);   // T1 XCD swizzle
  int rt = swz >> 2;                   // OUT_F/BN = 4 col tiles
  int ct = swz & 3;

  int tid = threadIdx.x;
  int lane = tid & 63;
  int w = tid >> 6;                    // 0..7
  int wr = w >> 2;                     // 0..1
  int wc = w & 3;                      // 0..3

  const char* Ab = (const char*)A + (size_t)rt * BM * RS;
  const char* Bb = (const char*)Bw + (size_t)ct * BN * RS;

  // staging geometry
  int srow = tid >> 3;                                   // 0..63
  int skb = ((tid & 7) << 4) ^ (((tid >> 3) & 7) << 4);  // inverse swizzle

  // read-side geometry
  int lane15 = lane & 15;
  int cb = lane >> 4;
  int swzm = (lane15 & 7) << 4;
  int kb0 = (cb << 4) ^ swzm;          // ks=0 swizzled K-byte
  int kb1 = (64 + (cb << 4)) ^ swzm;   // ks=1
  const char* aRow = lds + 32768 + (wr * 128 + lane15) * 128;
  const char* bRow = lds + (wc * 64 + lane15) * 128;

  f32x4 acc[8][4];
#pragma unroll
  for (int m = 0; m < 8; ++m)
#pragma unroll
    for (int n = 0; n < 4; ++n) acc[m][n] = {0.f, 0.f, 0.f, 0.f};

  // prologue: B0(0),B1(0),A0(0),A1(0),B0(1),B1(1) in pinned order
#pragma unroll
  for (int hp = 0; hp < 6; ++hp) {
    STAGE_HALF(hp);
    __builtin_amdgcn_sched_barrier(0);
  }
  asm volatile("s_waitcnt vmcnt(4)" ::: "memory");   // tile 0 landed
  __builtin_amdgcn_s_barrier();                      // ... for ALL waves

  for (int kt = 0; kt < NKT; kt += 2) {
    KTILE_BODY(kt, 0);
    KTILE_BODY(kt + 1, 65536);
  }

  // epilogue: C row = (lane>>4)*4 + j, col = lane&15 (m89 layout); bf16 store
  int crow0 = rt * BM + wr * 128 + (cb << 2);
  int ccol0 = ct * BN + wc * 64 + lane15;
#pragma unroll
  for (int m = 0; m < 8; ++m)
#pragma unroll
    for (int n = 0; n < 4; ++n)
#pragma unroll
      for (int j = 0; j < 4; ++j)
        Cb[(size_t)(crow0 + m * 16 + j) * OUT_F + ccol0 + n * 16] =
            f32_to_bf16_bits(acc[m][n][j]);
}

// ---------------- k3: LayerNorm, bf16 C -> fp32 out ----------------
__global__ __launch_bounds__(256) void ln_kernel(
    const unsigned short* __restrict__ Cb, float* __restrict__ out,
    const float* __restrict__ gamma, const float* __restrict__ beta) {
  int r = blockIdx.x;
  int t = threadIdx.x;
  ushort4 u = reinterpret_cast<const ushort4*>(Cb + (size_t)r * OUT_F)[t];
  float4 v;
  v.x = bf16_bits_to_f32(u.x);
  v.y = bf16_bits_to_f32(u.y);
  v.z = bf16_bits_to_f32(u.z);
  v.w = bf16_bits_to_f32(u.w);
  float s = v.x + v.y + v.z + v.w;
  float s2 = v.x * v.x + v.y * v.y + v.z * v.z + v.w * v.w;
#pragma unroll
  for (int off = 32; off > 0; off >>= 1) {
    s += __shfl_down(s, off, 64);
    s2 += __shfl_down(s2, off, 64);
  }
  __shared__ float ps[4], ps2[4];
  int lane = t & 63, wid = t >> 6;
  if (lane == 0) { ps[wid] = s; ps2[wid] = s2; }
  __syncthreads();
  float fs = ps[0] + ps[1] + ps[2] + ps[3];
  float fs2 = ps2[0] + ps2[1] + ps2[2] + ps2[3];
  float mu = fs * (1.0f / OUT_F);
  float var = fs2 * (1.0f / OUT_F) - mu * mu;
  float rstd = rsqrtf(var + EPS_LN);
  float4 g = reinterpret_cast<const float4*>(gamma)[t];
  float4 b = reinterpret_cast<const float4*>(beta)[t];
  float4 o;
  o.x = (v.x - mu) * rstd * g.x + b.x;
  o.y = (v.y - mu) * rstd * g.y + b.y;
  o.z = (v.z - mu) * rstd * g.z + b.z;
  o.w = (v.w - mu) * rstd * g.w + b.w;
  reinterpret_cast<float4*>(out + (size_t)r * OUT_F)[t] = o;
}

// ---------------- launch ----------------
extern "C" void kernel_launch(void* const* d_in, const int* in_sizes, int n_in,
                              void* d_out, int out_size, void* d_ws, size_t ws_size,
                              hipStream_t stream) {
  const float* x           = (const float*)d_in[0];
  const int*   idx_i       = (const int*)d_in[1];
  const int*   idx_j       = (const int*)d_in[2];
  const float* scale       = (const float*)d_in[3];
  const float* translation = (const float*)d_in[4];
  const float* lw          = (const float*)d_in[5];
  const float* w1          = (const float*)d_in[6];
  const float* gamma       = (const float*)d_in[7];
  const float* beta        = (const float*)d_in[8];
  float* out = (float*)d_out;

  unsigned short* Wcat = (unsigned short*)d_ws;
  size_t wcat_bytes = (size_t)OUT_F * KTOT * 2;          // 10.5 MB
  size_t avail = ws_size > wcat_bytes ? ws_size - wcat_bytes : 0;

  // per-chunk: Xcat chunk*KTOT*2 + Cb chunk*OUT_F*2 bytes
  int chunk = BATCH_N;
  while (chunk > 512 && (size_t)chunk * (KTOT * 2 + OUT_F * 2) > avail) chunk >>= 1;

  unsigned short* Cb = (unsigned short*)((char*)d_ws + wcat_bytes);
  unsigned short* Xcat = Cb + (size_t)chunk * OUT_F;

  prep_w_kernel<<<dim3(OUT_F * KTOT / 4 / 256), dim3(256), 0, stream>>>(lw, w1, Wcat);

  for (int rb = 0; rb < BATCH_N; rb += chunk) {
    prep_x_kernel<<<dim3(chunk), dim3(256), 0, stream>>>(
        x, idx_i, idx_j, scale, translation, Xcat, rb);
    gemm_kernel<<<dim3((chunk / BM) * (OUT_F / BN)), dim3(512), 0, stream>>>(
        Xcat, Wcat, Cb);
    ln_kernel<<<dim3(chunk), dim3(256), 0, stream>>>(
        Cb, out + (size_t)rb * OUT_F, gamma, beta);
  }
}